// Round 9
// baseline (78.970 us; speedup 1.0000x reference)
//
#include <hip/hip_runtime.h>

// out[n, lm, c] = sum_{e: recv[e]==n} node_feats[send[e], c] * edge_attrs[e, lm]
//                 * tp_weights[e, L_MAP[lm], c]
// receiver_list sorted; first_occ[n] = segment start. No atomics.
// Structure: one 128-thread block per node, thread = channel, scalar dword
// loads (256 B/wave coalesced), NT on stream-once traffic (tp_weights, out).
// R9 deltas (occupancy + chain-breaking, one theory):
//  (1) edge_attrs loads sunk into the compute phase (cached, short-latency,
//      hidden under tw-wait) -> ~48 fewer live VGPRs in the load burst;
//  (2) __launch_bounds__(128, 6): cap VGPR ~85 -> 6 waves/SIMD;
//  (3) 1-group lookahead prefetch of sender indices + gathers (branchless,
//      named registers only — no runtime-indexed arrays, no in-body branch).

typedef float f32x4 __attribute__((ext_vector_type(4)));

__device__ __forceinline__ void edge_fmas(float (&acc)[16], const float sf,
                                          const float t0, const float t1,
                                          const float t2, const float t3,
                                          const f32x4 ea0, const f32x4 ea1,
                                          const f32x4 ea2, const f32x4 ea3) {
    const float p0 = sf * t0;
    const float p1 = sf * t1;
    const float p2 = sf * t2;
    const float p3 = sf * t3;
    // L_MAP = [0, 1,1,1, 2,2,2,2,2, 3,3,3,3,3,3,3]
    acc[0]  = fmaf(p0, ea0.x, acc[0]);
    acc[1]  = fmaf(p1, ea0.y, acc[1]);
    acc[2]  = fmaf(p1, ea0.z, acc[2]);
    acc[3]  = fmaf(p1, ea0.w, acc[3]);
    acc[4]  = fmaf(p2, ea1.x, acc[4]);
    acc[5]  = fmaf(p2, ea1.y, acc[5]);
    acc[6]  = fmaf(p2, ea1.z, acc[6]);
    acc[7]  = fmaf(p2, ea1.w, acc[7]);
    acc[8]  = fmaf(p2, ea2.x, acc[8]);
    acc[9]  = fmaf(p3, ea2.y, acc[9]);
    acc[10] = fmaf(p3, ea2.z, acc[10]);
    acc[11] = fmaf(p3, ea2.w, acc[11]);
    acc[12] = fmaf(p3, ea3.x, acc[12]);
    acc[13] = fmaf(p3, ea3.y, acc[13]);
    acc[14] = fmaf(p3, ea3.z, acc[14]);
    acc[15] = fmaf(p3, ea3.w, acc[15]);
}

__global__ __launch_bounds__(128, 6)
void impt_kernel(const float* __restrict__ node_feats,
                 const float* __restrict__ edge_attrs,
                 const float* __restrict__ tp_weights,
                 const int*   __restrict__ sender_list,
                 const int*   __restrict__ first_occ,
                 float*       __restrict__ out,
                 int nnodes, int nedges)
{
    const int n = blockIdx.x;
    const int c = threadIdx.x;                 // 0..127 = channel
    const int start = first_occ[n];
    const int end   = (n + 1 < nnodes) ? first_occ[n + 1] : nedges;

    float acc[16];
#pragma unroll
    for (int i = 0; i < 16; ++i) acc[i] = 0.0f;

    const float* nf = node_feats + c;
    const float* tw = tp_weights + c;

    const int nIters = (end - start) >> 2;     // 4-edge groups
    int e = start;

    if (nIters > 0) {
        // ---- prologue: indices + gathers for group 0 ----
        int   i0 = sender_list[e];
        int   i1 = sender_list[e + 1];
        int   i2 = sender_list[e + 2];
        int   i3 = sender_list[e + 3];
        float g0 = nf[(size_t)i0 * 128];
        float g1 = nf[(size_t)i1 * 128];
        float g2 = nf[(size_t)i2 * 128];
        float g3 = nf[(size_t)i3 * 128];

        for (int it = 0; it < nIters; ++it, e += 4) {
            // current group's gathered sender features
            const float cg0 = g0, cg1 = g1, cg2 = g2, cg3 = g3;

            // ---- prefetch NEXT group's indices + gathers (branchless) ----
            const int p = (it + 1 < nIters) ? (e + 4) : e;   // uniform select
            i0 = sender_list[p];
            i1 = sender_list[p + 1];
            i2 = sender_list[p + 2];
            i3 = sender_list[p + 3];
            g0 = nf[(size_t)i0 * 128];
            g1 = nf[(size_t)i1 * 128];
            g2 = nf[(size_t)i2 * 128];
            g3 = nf[(size_t)i3 * 128];

            // ---- 16 NT tp_weights loads for the current group ----
            const float* tw0 = tw + (size_t)e * 512;
            const float* tw1 = tw0 + 512;
            const float* tw2 = tw0 + 1024;
            const float* tw3 = tw0 + 1536;
            const float tA0 = __builtin_nontemporal_load(tw0);
            const float tA1 = __builtin_nontemporal_load(tw0 + 128);
            const float tA2 = __builtin_nontemporal_load(tw0 + 256);
            const float tA3 = __builtin_nontemporal_load(tw0 + 384);
            const float tB0 = __builtin_nontemporal_load(tw1);
            const float tB1 = __builtin_nontemporal_load(tw1 + 128);
            const float tB2 = __builtin_nontemporal_load(tw1 + 256);
            const float tB3 = __builtin_nontemporal_load(tw1 + 384);
            const float tC0 = __builtin_nontemporal_load(tw2);
            const float tC1 = __builtin_nontemporal_load(tw2 + 128);
            const float tC2 = __builtin_nontemporal_load(tw2 + 256);
            const float tC3 = __builtin_nontemporal_load(tw2 + 384);
            const float tD0 = __builtin_nontemporal_load(tw3);
            const float tD1 = __builtin_nontemporal_load(tw3 + 128);
            const float tD2 = __builtin_nontemporal_load(tw3 + 256);
            const float tD3 = __builtin_nontemporal_load(tw3 + 384);

            // ---- compute phase: ea loads (cached) sunk next to their FMAs ----
            const f32x4* ea = reinterpret_cast<const f32x4*>(edge_attrs + (size_t)e * 16);
            {
                const f32x4 a0 = ea[0], a1 = ea[1], a2 = ea[2], a3 = ea[3];
                edge_fmas(acc, cg0, tA0, tA1, tA2, tA3, a0, a1, a2, a3);
            }
            {
                const f32x4 b0 = ea[4], b1 = ea[5], b2 = ea[6], b3 = ea[7];
                edge_fmas(acc, cg1, tB0, tB1, tB2, tB3, b0, b1, b2, b3);
            }
            {
                const f32x4 c0 = ea[8], c1 = ea[9], c2 = ea[10], c3 = ea[11];
                edge_fmas(acc, cg2, tC0, tC1, tC2, tC3, c0, c1, c2, c3);
            }
            {
                const f32x4 d0 = ea[12], d1 = ea[13], d2 = ea[14], d3 = ea[15];
                edge_fmas(acc, cg3, tD0, tD1, tD2, tD3, d0, d1, d2, d3);
            }
        }
    }

    // ---- tail: up to 3 single edges ----
    for (; e < end; ++e) {
        const int s = sender_list[e];
        const float sf = nf[(size_t)s * 128];
        const float* twp = tw + (size_t)e * 512;
        const float t0 = __builtin_nontemporal_load(twp);
        const float t1 = __builtin_nontemporal_load(twp + 128);
        const float t2 = __builtin_nontemporal_load(twp + 256);
        const float t3 = __builtin_nontemporal_load(twp + 384);
        const f32x4* ea = reinterpret_cast<const f32x4*>(edge_attrs + (size_t)e * 16);
        edge_fmas(acc, sf, t0, t1, t2, t3, ea[0], ea[1], ea[2], ea[3]);
    }

    // coalesced NT stores (zeros if node has no edges)
    float* o = out + (size_t)n * 2048 + c;
#pragma unroll
    for (int lm = 0; lm < 16; ++lm) {
        __builtin_nontemporal_store(acc[lm], o + (size_t)lm * 128);
    }
}

extern "C" void kernel_launch(void* const* d_in, const int* in_sizes, int n_in,
                              void* d_out, int out_size, void* d_ws, size_t ws_size,
                              hipStream_t stream)
{
    const float* node_feats  = (const float*)d_in[0];
    const float* edge_attrs  = (const float*)d_in[1];
    const float* tp_weights  = (const float*)d_in[2];
    const int*   sender_list = (const int*)d_in[3];
    // d_in[4] = receiver_list (unused; first_occurences encodes the segments)
    const int*   first_occ   = (const int*)d_in[5];

    const int nnodes = in_sizes[5];          // 10000
    const int nedges = in_sizes[3];          // 160000

    impt_kernel<<<nnodes, 128, 0, stream>>>(node_feats, edge_attrs, tp_weights,
                                            sender_list, first_occ,
                                            (float*)d_out, nnodes, nedges);
}